// Round 5
// baseline (458.805 us; speedup 1.0000x reference)
//
#include <hip/hip_runtime.h>

#define NN 4096

typedef __attribute__((ext_vector_type(8))) short short8;
typedef __attribute__((ext_vector_type(4))) float f32x4;

// fp32 -> bf16 round-to-nearest-even
static __device__ __forceinline__ unsigned short f2bf(float x) {
    unsigned int u = __float_as_uint(x);
    u += 0x7fffu + ((u >> 16) & 1u);
    return (unsigned short)(u >> 16);
}

// async global->LDS, 16 bytes per lane (dest = wave-uniform base + lane*16)
static __device__ __forceinline__ void load_lds16(const unsigned short* g, unsigned short* l) {
    __builtin_amdgcn_global_load_lds(
        (const __attribute__((address_space(1))) unsigned int*)g,
        (__attribute__((address_space(3))) unsigned int*)l,
        16, 0, 0);
}

// XOR-swizzled byte offset inside one 16KB K-subtile (256 rows x 32 k bf16, row = 64B).
// phys = logical ^ (((logical>>7)&7)<<4): involution on 16B chunks within 128B pairs.
// Verified round 3/4: SQ_LDS_BANK_CONFLICT = 0.
static __device__ __forceinline__ int swz_byte(int row, int byte_in_row) {
    return (row * 64 + byte_in_row) ^ (((row >> 1) & 7) << 4);
}

// ---------------- fused pre-pass: pack A & B (tiled+swizzled bf16) + zero C tiles ----------------
// A2 layout: [bi(16)][kb32(128)][16KB tile of 256 rows x 32 k], only kb32 < (bi+1)*8 written.
// B2 layout: [bjn(16)][kb32(128)][16KB tile of 256 n-rows x 32 k] (B^T), kb32 >= bjn*8.
// blocks [0,1088): B pack (heavy, first); [1088,2176): A pack; [2176,2401): zero C tiles
// (120 strict-upper + 105 lower tiles with D>=2 that receive atomic partials).
__global__ __launch_bounds__(256) void prep_all(const float* __restrict__ A,
                                                const float* __restrict__ B,
                                                unsigned short* __restrict__ A2,
                                                unsigned short* __restrict__ B2,
                                                float* __restrict__ C) {
    __shared__ unsigned short tbf[32][264];   // 16.5 KB
    const int b   = blockIdx.x;
    const int tid = threadIdx.x;

    if (b < 1088) {
        // ---- pack B tile (bjn, kb32): n rows bjn*256..+255, k = kb32*32..+31, mask k>=n ----
        int rem = b, bjn;
        for (bjn = 0; bjn < 16; ++bjn) { int cnt = 128 - bjn * 8; if (rem < cnt) break; rem -= cnt; }
        const int kb = bjn * 8 + rem;
        #pragma unroll
        for (int p = 0; p < 8; ++p) {
            int id   = p * 256 + tid;
            int krow = id >> 6;              // 0..31
            int c4   = (id & 63) << 2;       // 0..252
            const float4 v = *(const float4*)(B + (size_t)(kb * 32 + krow) * NN + bjn * 256 + c4);
            tbf[krow][c4 + 0] = f2bf(v.x); tbf[krow][c4 + 1] = f2bf(v.y);
            tbf[krow][c4 + 2] = f2bf(v.z); tbf[krow][c4 + 3] = f2bf(v.w);
        }
        __syncthreads();
        unsigned short* out = B2 + (size_t)bjn * 1048576 + (size_t)kb * 8192;
        const int n  = tid;
        const int ng = bjn * 256 + n;
        #pragma unroll
        for (int kc = 0; kc < 4; ++kc) {
            short8 o;
            #pragma unroll
            for (int e = 0; e < 8; ++e) {
                int kg = kb * 32 + kc * 8 + e;
                o[e] = (kg >= ng) ? (short)tbf[kc * 8 + e][n] : (short)0;
            }
            *(short8*)&out[swz_byte(n, kc * 16) >> 1] = o;
        }
    } else if (b < 2176) {
        // ---- pack A tile (bi, kb32): rows bi*256..+255, k = kb32*32..+31, mask k<=i ----
        int rem = b - 1088, bi;
        for (bi = 0; bi < 16; ++bi) { int cnt = (bi + 1) * 8; if (rem < cnt) break; rem -= cnt; }
        const int kb = rem;
        unsigned short* out = A2 + (size_t)bi * 1048576 + (size_t)kb * 8192;
        #pragma unroll
        for (int p = 0; p < 8; ++p) {
            int id  = p * 256 + tid;
            int row = id >> 3;               // 0..255
            int c4  = (id & 7) << 2;         // 0..28
            const int gi = bi * 256 + row;
            const int kg = kb * 32 + c4;
            const float4 v = *(const float4*)(A + (size_t)gi * NN + kg);
            ushort4 o;
            o.x = (kg + 0 <= gi) ? f2bf(v.x) : (unsigned short)0;
            o.y = (kg + 1 <= gi) ? f2bf(v.y) : (unsigned short)0;
            o.z = (kg + 2 <= gi) ? f2bf(v.z) : (unsigned short)0;
            o.w = (kg + 3 <= gi) ? f2bf(v.w) : (unsigned short)0;
            *(ushort4*)&out[swz_byte(row, c4 * 2) >> 1] = o;
        }
    } else {
        // ---- zero C tiles: 120 strict-upper + 105 lower (D>=2) ----
        int u = b - 2176;
        int ti, tj;
        if (u < 120) {
            for (tj = 1; tj < 16; ++tj) { if (u < tj) { ti = u; break; } u -= tj; }
        } else {
            u -= 120;
            int d2;
            for (d2 = 2; d2 < 16; ++d2) { int cnt = 16 - d2; if (u < cnt) break; u -= cnt; }
            tj = u; ti = u + d2;
        }
        const float4 z = make_float4(0.f, 0.f, 0.f, 0.f);
        #pragma unroll
        for (int it = 0; it < 64; ++it) {
            int idx = it * 256 + tid;
            int rr  = idx >> 6;              // 0..255
            int c4  = (idx & 63) << 2;       // 0..252
            *(float4*)&C[(size_t)(ti * 256 + rr) * NN + tj * 256 + c4] = z;
        }
    }
}

// ---------------- main GEMM: 256x256 tile, BK=64 single-buffer, 2 blocks/CU ----------------
// 444 near-uniform units (<=8 K64-steps): tile (bi,bj), D=bi-bj, m=(D>>1)+1 balanced chunks.
// 64KB LDS + <=128 VGPR (launch_bounds 512,4) -> 2 co-resident blocks/CU: inter-block overlap
// (m114) hides the per-step barrier drain — the mechanism r0 had and r3/r4 lost.
__global__ __launch_bounds__(512, 4) void gemm_tril(const unsigned short* __restrict__ A2,
                                                    const unsigned short* __restrict__ B2,
                                                    float* __restrict__ C) {
    const int tid = threadIdx.x;

    // bijective XCD-chunked map for 444 blocks: q=55, r=4
    const int bidx = (int)blockIdx.x;
    const int xcd = bidx & 7, ix = bidx >> 3;
    int u = (xcd < 4 ? xcd * 56 : 224 + (xcd - 4) * 55) + ix;

    // decode unit (deepest-D first) -> (D, tile, chunk); m = floor(D/2)+1
    int D, m = 1, rem = u;
    for (D = 15; D >= 0; --D) {
        m = (D >> 1) + 1;
        int cnt = (16 - D) * m;
        if (rem < cnt) break;
        rem -= cnt;
    }
    const int blk = rem / m;
    const int c   = rem - blk * m;
    const int bj = blk, bi = blk + D;
    const int S64 = (D + 1) * 4;             // K64-steps of the whole tile
    const int kt0 = bj * 4 + (c * S64) / m;
    const int kt1 = bj * 4 + ((c + 1) * S64) / m;

    __shared__ __attribute__((aligned(16))) unsigned short As[32768 / 2];  // 32KB: 256r x 64k
    __shared__ __attribute__((aligned(16))) unsigned short Bs[32768 / 2];  // 32KB

    const int lane = tid & 63;
    const int w    = tid >> 6;               // 0..7
    const int wm   = w >> 2, wn = w & 3;     // 2 x 4 wave grid: 128 x 64 per wave
    const int l15  = lane & 15, quad = lane >> 4;

    f32x4 acc[8][4];
    const f32x4 zero4 = {0.f, 0.f, 0.f, 0.f};
    #pragma unroll
    for (int i = 0; i < 8; ++i)
        #pragma unroll
        for (int j = 0; j < 4; ++j) acc[i][j] = zero4;

    // one BK=64 step = two consecutive packed 16KB subtiles = 32KB contiguous per matrix
    const unsigned short* Atile = A2 + (size_t)bi * 1048576 + tid * 8;
    const unsigned short* Btile = B2 + (size_t)bj * 1048576 + tid * 8;

    for (int kt = kt0; kt < kt1; ++kt) {
        const unsigned short* ga = Atile + (size_t)kt * 16384;
        const unsigned short* gb = Btile + (size_t)kt * 16384;
        #pragma unroll
        for (int r = 0; r < 4; ++r) {
            load_lds16(ga + r * 4096, &As[tid * 8 + r * 4096]);
            load_lds16(gb + r * 4096, &Bs[tid * 8 + r * 4096]);
        }
        __syncthreads();

        #pragma unroll
        for (int h = 0; h < 2; ++h) {        // two 16KB k-halves of the BK=64 step
            short8 a[8], bq[4];
            #pragma unroll
            for (int mt = 0; mt < 8; ++mt) {
                int r = wm * 128 + mt * 16 + l15;
                a[mt] = *(const short8*)&As[h * 8192 + (swz_byte(r, quad * 16) >> 1)];
            }
            #pragma unroll
            for (int nt2 = 0; nt2 < 4; ++nt2) {
                int r = wn * 64 + nt2 * 16 + l15;
                bq[nt2] = *(const short8*)&Bs[h * 8192 + (swz_byte(r, quad * 16) >> 1)];
            }
            #pragma unroll
            for (int mt = 0; mt < 8; ++mt)
                #pragma unroll
                for (int nt2 = 0; nt2 < 4; ++nt2)
                    acc[mt][nt2] = __builtin_amdgcn_mfma_f32_16x16x32_bf16(a[mt], bq[nt2], acc[mt][nt2], 0, 0, 0);
        }
        __syncthreads();
    }

    // epilogue: C/D layout col=lane&15, row=quad*4+reg (m89-verified)
    if (m == 1) {
        // D<=1: sole owner, direct store (diagonal mask only when D==0)
        #pragma unroll
        for (int mt = 0; mt < 8; ++mt) {
            #pragma unroll
            for (int nt2 = 0; nt2 < 4; ++nt2) {
                const int gj  = bj * 256 + wn * 64 + nt2 * 16 + l15;
                const int gi0 = bi * 256 + wm * 128 + mt * 16 + quad * 4;
                #pragma unroll
                for (int rr = 0; rr < 4; ++rr) {
                    int gi = gi0 + rr;
                    float v = acc[mt][nt2][rr];
                    C[(size_t)gi * NN + gj] = (D > 0 || gi >= gj) ? v : 0.f;
                }
            }
        }
    } else {
        // partial contribution: tile pre-zeroed in prep; D>=2 so strictly lower, no mask
        #pragma unroll
        for (int mt = 0; mt < 8; ++mt) {
            #pragma unroll
            for (int nt2 = 0; nt2 < 4; ++nt2) {
                const int gj  = bj * 256 + wn * 64 + nt2 * 16 + l15;
                const int gi0 = bi * 256 + wm * 128 + mt * 16 + quad * 4;
                #pragma unroll
                for (int rr = 0; rr < 4; ++rr) {
                    int gi = gi0 + rr;
                    atomicAdd(&C[(size_t)gi * NN + gj], acc[mt][nt2][rr]);
                }
            }
        }
    }
}

// ---------------- fallback (ws too small): fp32 LDS-tiled, correct-but-slow ----------------
__global__ void gemm_fallback(const float* __restrict__ A, const float* __restrict__ B,
                              float* __restrict__ C) {
    const int bi = blockIdx.y, bj = blockIdx.x;
    const int ty = threadIdx.y, tx = threadIdx.x;
    const int gi = bi * 32 + ty, gj = bj * 32 + tx;
    if (bi < bj) { C[(size_t)gi * NN + gj] = 0.f; return; }
    __shared__ float As[32][33], Bs[32][33];
    float s = 0.f;
    for (int kt = bj; kt <= bi; ++kt) {
        const int k = kt * 32;
        float av = A[(size_t)gi * NN + k + tx];
        As[ty][tx] = (k + tx <= gi) ? av : 0.f;
        float bv = B[(size_t)(k + ty) * NN + gj];
        Bs[ty][tx] = (k + ty >= gj) ? bv : 0.f;
        __syncthreads();
        #pragma unroll
        for (int kk = 0; kk < 32; ++kk) s += As[ty][kk] * Bs[kk][tx];
        __syncthreads();
    }
    C[(size_t)gi * NN + gj] = (gi >= gj) ? s : 0.f;
}

extern "C" void kernel_launch(void* const* d_in, const int* in_sizes, int n_in,
                              void* d_out, int out_size, void* d_ws, size_t ws_size,
                              hipStream_t stream) {
    const float* A = (const float*)d_in[0];
    const float* B = (const float*)d_in[1];
    float* C = (float*)d_out;

    const size_t need = (size_t)2 * NN * NN * sizeof(unsigned short);  // 64 MB
    if (ws_size >= need) {
        unsigned short* A2 = (unsigned short*)d_ws;
        unsigned short* B2 = A2 + (size_t)NN * NN;
        prep_all<<<dim3(2401), dim3(256), 0, stream>>>(A, B, A2, B2, C);
        gemm_tril<<<dim3(444), dim3(512), 0, stream>>>(A2, B2, C);
    } else {
        gemm_fallback<<<dim3(128, 128), dim3(32, 32), 0, stream>>>(A, B, C);
    }
}

// Round 6
// 298.011 us; speedup vs baseline: 1.5396x; 1.5396x over previous
//
#include <hip/hip_runtime.h>

#define NN 4096

typedef __attribute__((ext_vector_type(8))) short short8;
typedef __attribute__((ext_vector_type(4))) float f32x4;

// fp32 -> bf16 round-to-nearest-even
static __device__ __forceinline__ unsigned short f2bf(float x) {
    unsigned int u = __float_as_uint(x);
    u += 0x7fffu + ((u >> 16) & 1u);
    return (unsigned short)(u >> 16);
}

// async global->LDS, 16 bytes per lane (dest = wave-uniform base + lane*16)
static __device__ __forceinline__ void load_lds16(const unsigned short* g, unsigned short* l) {
    __builtin_amdgcn_global_load_lds(
        (const __attribute__((address_space(1))) unsigned int*)g,
        (__attribute__((address_space(3))) unsigned int*)l,
        16, 0, 0);
}

// XOR-swizzled byte offset inside one 16KB K-subtile (256 rows x 32 k bf16, row = 64B).
// phys = logical ^ (((logical>>7)&7)<<4): involution on 16B chunks within 128B pairs.
// Verified rounds 3/4: SQ_LDS_BANK_CONFLICT = 0.
static __device__ __forceinline__ int swz_byte(int row, int byte_in_row) {
    return (row * 64 + byte_in_row) ^ (((row >> 1) & 7) << 4);
}

// ---------------- fused pre-pass: pack A & B (tiled+swizzled bf16) + zero C tiles ----------------
// A2 layout: [bi(16)][kb32(128)][16KB tile of 256 rows x 32 k], only kb32 < (bi+1)*8 written.
// B2 layout: [bjn(16)][kb32(128)][16KB tile of 256 n-rows x 32 k] (B^T), kb32 >= bjn*8.
// blocks [0,1088): B pack (heavy, first); [1088,2176): A pack; [2176,2401): zero C tiles
// (120 strict-upper + 105 lower tiles with D>=2 that receive atomic partials).
__global__ __launch_bounds__(256) void prep_all(const float* __restrict__ A,
                                                const float* __restrict__ B,
                                                unsigned short* __restrict__ A2,
                                                unsigned short* __restrict__ B2,
                                                float* __restrict__ C) {
    __shared__ unsigned short tbf[32][264];   // 16.5 KB
    const int b   = blockIdx.x;
    const int tid = threadIdx.x;

    if (b < 1088) {
        // ---- pack B tile (bjn, kb32): n rows bjn*256..+255, k = kb32*32..+31, mask k>=n ----
        int rem = b, bjn;
        for (bjn = 0; bjn < 16; ++bjn) { int cnt = 128 - bjn * 8; if (rem < cnt) break; rem -= cnt; }
        const int kb = bjn * 8 + rem;
        #pragma unroll
        for (int p = 0; p < 8; ++p) {
            int id   = p * 256 + tid;
            int krow = id >> 6;              // 0..31
            int c4   = (id & 63) << 2;       // 0..252
            const float4 v = *(const float4*)(B + (size_t)(kb * 32 + krow) * NN + bjn * 256 + c4);
            tbf[krow][c4 + 0] = f2bf(v.x); tbf[krow][c4 + 1] = f2bf(v.y);
            tbf[krow][c4 + 2] = f2bf(v.z); tbf[krow][c4 + 3] = f2bf(v.w);
        }
        __syncthreads();
        unsigned short* out = B2 + (size_t)bjn * 1048576 + (size_t)kb * 8192;
        const int n  = tid;
        const int ng = bjn * 256 + n;
        #pragma unroll
        for (int kc = 0; kc < 4; ++kc) {
            short8 o;
            #pragma unroll
            for (int e = 0; e < 8; ++e) {
                int kg = kb * 32 + kc * 8 + e;
                o[e] = (kg >= ng) ? (short)tbf[kc * 8 + e][n] : (short)0;
            }
            *(short8*)&out[swz_byte(n, kc * 16) >> 1] = o;
        }
    } else if (b < 2176) {
        // ---- pack A tile (bi, kb32): rows bi*256..+255, k = kb32*32..+31, mask k<=i ----
        int rem = b - 1088, bi;
        for (bi = 0; bi < 16; ++bi) { int cnt = (bi + 1) * 8; if (rem < cnt) break; rem -= cnt; }
        const int kb = rem;
        unsigned short* out = A2 + (size_t)bi * 1048576 + (size_t)kb * 8192;
        #pragma unroll
        for (int p = 0; p < 8; ++p) {
            int id  = p * 256 + tid;
            int row = id >> 3;               // 0..255
            int c4  = (id & 7) << 2;         // 0..28
            const int gi = bi * 256 + row;
            const int kg = kb * 32 + c4;
            const float4 v = *(const float4*)(A + (size_t)gi * NN + kg);
            ushort4 o;
            o.x = (kg + 0 <= gi) ? f2bf(v.x) : (unsigned short)0;
            o.y = (kg + 1 <= gi) ? f2bf(v.y) : (unsigned short)0;
            o.z = (kg + 2 <= gi) ? f2bf(v.z) : (unsigned short)0;
            o.w = (kg + 3 <= gi) ? f2bf(v.w) : (unsigned short)0;
            *(ushort4*)&out[swz_byte(row, c4 * 2) >> 1] = o;
        }
    } else {
        // ---- zero C tiles: 120 strict-upper + 105 lower (D>=2) ----
        int u = b - 2176;
        int ti, tj;
        if (u < 120) {
            for (tj = 1; tj < 16; ++tj) { if (u < tj) { ti = u; break; } u -= tj; }
        } else {
            u -= 120;
            int d2;
            for (d2 = 2; d2 < 16; ++d2) { int cnt = 16 - d2; if (u < cnt) break; u -= cnt; }
            tj = u; ti = u + d2;
        }
        const float4 z = make_float4(0.f, 0.f, 0.f, 0.f);
        #pragma unroll
        for (int it = 0; it < 64; ++it) {
            int idx = it * 256 + tid;
            int rr  = idx >> 6;              // 0..255
            int c4  = (idx & 63) << 2;       // 0..252
            *(float4*)&C[(size_t)(ti * 256 + rr) * NN + tj * 256 + c4] = z;
        }
    }
}

// ---------------- main GEMM: 256x256 tile, BK=64 single-buffer, 2 blocks/CU ----------------
// 444 near-uniform units (4..8 K64-steps): tile (bi,bj), D=bi-bj, m=(D>>1)+1 balanced chunks.
// 64KB LDS; launch_bounds(512,2) -> compiler's natural 112-VGPR allocation (r4-verified,
// NO spill) which permits 4 waves/SIMD = 2 co-resident 8-wave blocks/CU. Inter-block overlap
// (m114) hides the per-step barrier drain. (r5's (512,4) forced VGPR=64 + acc spill: -2.5x.)
__global__ __launch_bounds__(512, 2) void gemm_tril(const unsigned short* __restrict__ A2,
                                                    const unsigned short* __restrict__ B2,
                                                    float* __restrict__ C) {
    const int tid = threadIdx.x;

    // bijective XCD-chunked map for 444 blocks: q=55, r=4
    const int bidx = (int)blockIdx.x;
    const int xcd = bidx & 7, ix = bidx >> 3;
    int u = (xcd < 4 ? xcd * 56 : 224 + (xcd - 4) * 55) + ix;

    // decode unit (deepest-D first) -> (D, tile, chunk); m = floor(D/2)+1
    int D, m = 1, rem = u;
    for (D = 15; D >= 0; --D) {
        m = (D >> 1) + 1;
        int cnt = (16 - D) * m;
        if (rem < cnt) break;
        rem -= cnt;
    }
    const int blk = rem / m;
    const int c   = rem - blk * m;
    const int bj = blk, bi = blk + D;
    const int S64 = (D + 1) * 4;             // K64-steps of the whole tile
    const int kt0 = bj * 4 + (c * S64) / m;
    const int kt1 = bj * 4 + ((c + 1) * S64) / m;

    __shared__ __attribute__((aligned(16))) unsigned short As[16384];  // 32KB: 256r x 64k
    __shared__ __attribute__((aligned(16))) unsigned short Bs[16384];  // 32KB

    const int lane = tid & 63;
    const int w    = tid >> 6;               // 0..7
    const int wm   = w >> 2, wn = w & 3;     // 2 x 4 wave grid: 128 x 64 per wave
    const int l15  = lane & 15, quad = lane >> 4;

    f32x4 acc[8][4];
    const f32x4 zero4 = {0.f, 0.f, 0.f, 0.f};
    #pragma unroll
    for (int i = 0; i < 8; ++i)
        #pragma unroll
        for (int j = 0; j < 4; ++j) acc[i][j] = zero4;

    // one BK=64 step = two consecutive packed 16KB subtiles = 32KB contiguous per matrix
    const unsigned short* Atile = A2 + (size_t)bi * 1048576 + tid * 8;
    const unsigned short* Btile = B2 + (size_t)bj * 1048576 + tid * 8;

    for (int kt = kt0; kt < kt1; ++kt) {
        const unsigned short* ga = Atile + (size_t)kt * 16384;
        const unsigned short* gb = Btile + (size_t)kt * 16384;
        #pragma unroll
        for (int r = 0; r < 4; ++r) {
            load_lds16(ga + r * 4096, &As[tid * 8 + r * 4096]);
            load_lds16(gb + r * 4096, &Bs[tid * 8 + r * 4096]);
        }
        __syncthreads();

        #pragma unroll
        for (int h = 0; h < 2; ++h) {        // two 16KB k-halves of the BK=64 step
            short8 a[8], bq[4];
            #pragma unroll
            for (int mt = 0; mt < 8; ++mt) {
                int r = wm * 128 + mt * 16 + l15;
                a[mt] = *(const short8*)&As[h * 8192 + (swz_byte(r, quad * 16) >> 1)];
            }
            #pragma unroll
            for (int nt2 = 0; nt2 < 4; ++nt2) {
                int r = wn * 64 + nt2 * 16 + l15;
                bq[nt2] = *(const short8*)&Bs[h * 8192 + (swz_byte(r, quad * 16) >> 1)];
            }
            #pragma unroll
            for (int mt = 0; mt < 8; ++mt)
                #pragma unroll
                for (int nt2 = 0; nt2 < 4; ++nt2)
                    acc[mt][nt2] = __builtin_amdgcn_mfma_f32_16x16x32_bf16(a[mt], bq[nt2], acc[mt][nt2], 0, 0, 0);
        }
        __syncthreads();
    }

    // epilogue: C/D layout col=lane&15, row=quad*4+reg (m89-verified)
    if (m == 1) {
        // D<=1: sole owner, direct store (diagonal mask only when D==0)
        #pragma unroll
        for (int mt = 0; mt < 8; ++mt) {
            #pragma unroll
            for (int nt2 = 0; nt2 < 4; ++nt2) {
                const int gj  = bj * 256 + wn * 64 + nt2 * 16 + l15;
                const int gi0 = bi * 256 + wm * 128 + mt * 16 + quad * 4;
                #pragma unroll
                for (int rr = 0; rr < 4; ++rr) {
                    int gi = gi0 + rr;
                    float v = acc[mt][nt2][rr];
                    C[(size_t)gi * NN + gj] = (D > 0 || gi >= gj) ? v : 0.f;
                }
            }
        }
    } else {
        // partial contribution: tile pre-zeroed in prep; D>=2 so strictly lower, no mask
        #pragma unroll
        for (int mt = 0; mt < 8; ++mt) {
            #pragma unroll
            for (int nt2 = 0; nt2 < 4; ++nt2) {
                const int gj  = bj * 256 + wn * 64 + nt2 * 16 + l15;
                const int gi0 = bi * 256 + wm * 128 + mt * 16 + quad * 4;
                #pragma unroll
                for (int rr = 0; rr < 4; ++rr) {
                    int gi = gi0 + rr;
                    atomicAdd(&C[(size_t)gi * NN + gj], acc[mt][nt2][rr]);
                }
            }
        }
    }
}

// ---------------- fallback (ws too small): fp32 LDS-tiled, correct-but-slow ----------------
__global__ void gemm_fallback(const float* __restrict__ A, const float* __restrict__ B,
                              float* __restrict__ C) {
    const int bi = blockIdx.y, bj = blockIdx.x;
    const int ty = threadIdx.y, tx = threadIdx.x;
    const int gi = bi * 32 + ty, gj = bj * 32 + tx;
    if (bi < bj) { C[(size_t)gi * NN + gj] = 0.f; return; }
    __shared__ float As[32][33], Bs[32][33];
    float s = 0.f;
    for (int kt = bj; kt <= bi; ++kt) {
        const int k = kt * 32;
        float av = A[(size_t)gi * NN + k + tx];
        As[ty][tx] = (k + tx <= gi) ? av : 0.f;
        float bv = B[(size_t)(k + ty) * NN + gj];
        Bs[ty][tx] = (k + ty >= gj) ? bv : 0.f;
        __syncthreads();
        #pragma unroll
        for (int kk = 0; kk < 32; ++kk) s += As[ty][kk] * Bs[kk][tx];
        __syncthreads();
    }
    C[(size_t)gi * NN + gj] = (gi >= gj) ? s : 0.f;
}

extern "C" void kernel_launch(void* const* d_in, const int* in_sizes, int n_in,
                              void* d_out, int out_size, void* d_ws, size_t ws_size,
                              hipStream_t stream) {
    const float* A = (const float*)d_in[0];
    const float* B = (const float*)d_in[1];
    float* C = (float*)d_out;

    const size_t need = (size_t)2 * NN * NN * sizeof(unsigned short);  // 64 MB
    if (ws_size >= need) {
        unsigned short* A2 = (unsigned short*)d_ws;
        unsigned short* B2 = A2 + (size_t)NN * NN;
        prep_all<<<dim3(2401), dim3(256), 0, stream>>>(A, B, A2, B2, C);
        gemm_tril<<<dim3(444), dim3(512), 0, stream>>>(A2, B2, C);
    } else {
        gemm_fallback<<<dim3(128, 128), dim3(32, 32), 0, stream>>>(A, B, C);
    }
}

// Round 7
// 221.491 us; speedup vs baseline: 2.0714x; 1.3455x over previous
//
#include <hip/hip_runtime.h>

#define NN 4096

typedef __attribute__((ext_vector_type(8))) short short8;
typedef __attribute__((ext_vector_type(4))) float f32x4;

// fp32 -> bf16 round-to-nearest-even
static __device__ __forceinline__ unsigned short f2bf(float x) {
    unsigned int u = __float_as_uint(x);
    u += 0x7fffu + ((u >> 16) & 1u);
    return (unsigned short)(u >> 16);
}

// async global->LDS, 16 bytes per lane (dest = wave-uniform base + lane*16)
static __device__ __forceinline__ void load_lds16(const unsigned short* g, unsigned short* l) {
    __builtin_amdgcn_global_load_lds(
        (const __attribute__((address_space(1))) unsigned int*)g,
        (__attribute__((address_space(3))) unsigned int*)l,
        16, 0, 0);
}

// XOR-swizzled byte offset inside one 8KB K-step tile (128 rows x 32 k bf16, row = 64B).
// phys = logical ^ (((row>>1)&7)<<4): involution on 16B chunks within 128B row-pairs.
// ds_read_b128 column reads (16 rows, 64B stride) spread across 8 16B slots -> 2-way (free).
// (Swizzle family verified rounds 3/4: SQ_LDS_BANK_CONFLICT = 0.)
static __device__ __forceinline__ int swz_byte(int row, int byte_in_row) {
    return (row * 64 + byte_in_row) ^ (((row >> 1) & 7) << 4);
}

// ---------------- fused pre-pass: pack A & B into 8KB swizzled tiles + zero C tiles ----------------
// A2 layout: [bi(32)][kb(128)][8KB = 128 rows x 32 k bf16, swizzled]; valid kb < (bi+1)*4.
// B2 layout: [bj(32)][kb(128)][8KB = 128 n-rows x 32 k bf16 (B^T), swizzled]; valid kb >= bj*4.
// blocks [0,2112): B pack (heavier: LDS transpose) ; [2112,4224): A pack ;
// [4224,5020): zero C tiles (496 strict-upper + 300 lower split tiles with d>=8).
__global__ __launch_bounds__(256) void prep_all(const float* __restrict__ A,
                                                const float* __restrict__ B,
                                                unsigned short* __restrict__ A2,
                                                unsigned short* __restrict__ B2,
                                                float* __restrict__ C) {
    __shared__ unsigned short tbf[32][132];   // 8.25 KB bf16 staging for B transpose
    const int b   = blockIdx.x;
    const int tid = threadIdx.x;

    if (b < 2112) {
        // ---- pack B tile (bj, kb): n rows bj*128..+127, k = kb*32..+31, mask k>=n ----
        int rem = b, bj;
        for (bj = 0; bj < 32; ++bj) { int cnt = 128 - bj * 4; if (rem < cnt) break; rem -= cnt; }
        const int kb = bj * 4 + rem;
        // stage 32(k) x 128(n) block of B, coalesced f32 reads, convert to bf16
        #pragma unroll
        for (int p = 0; p < 4; ++p) {
            int id   = p * 256 + tid;
            int krow = id >> 5;               // 0..31
            int c4   = (id & 31) << 2;        // 0..124
            const float4 v = *(const float4*)(B + (size_t)(kb * 32 + krow) * NN + bj * 128 + c4);
            tbf[krow][c4 + 0] = f2bf(v.x); tbf[krow][c4 + 1] = f2bf(v.y);
            tbf[krow][c4 + 2] = f2bf(v.z); tbf[krow][c4 + 3] = f2bf(v.w);
        }
        __syncthreads();
        unsigned short* out = B2 + ((size_t)bj * 128 + kb) * 4096;
        #pragma unroll
        for (int p = 0; p < 2; ++p) {
            int id = p * 256 + tid;
            int n  = id >> 2;                 // 0..127
            int kc = id & 3;                  // 0..3 (8-k group)
            const int ng = bj * 128 + n;
            short8 o;
            #pragma unroll
            for (int e = 0; e < 8; ++e) {
                int kg = kb * 32 + kc * 8 + e;
                o[e] = (kg >= ng) ? (short)tbf[kc * 8 + e][n] : (short)0;
            }
            *(short8*)&out[swz_byte(n, kc * 16) >> 1] = o;
        }
    } else if (b < 4224) {
        // ---- pack A tile (bi, kb): rows bi*128..+127, k = kb*32..+31, mask k<=i ----
        int rem = b - 2112, bi;
        for (bi = 0; bi < 32; ++bi) { int cnt = (bi + 1) * 4; if (rem < cnt) break; rem -= cnt; }
        const int kb = rem;
        unsigned short* out = A2 + ((size_t)bi * 128 + kb) * 4096;
        #pragma unroll
        for (int p = 0; p < 4; ++p) {
            int id  = p * 256 + tid;
            int row = id >> 3;                // 0..127
            int c4  = (id & 7) << 2;          // 0..28
            const int gi = bi * 128 + row;
            const int kg = kb * 32 + c4;
            const float4 v = *(const float4*)(A + (size_t)gi * NN + kg);
            ushort4 o;
            o.x = (kg + 0 <= gi) ? f2bf(v.x) : (unsigned short)0;
            o.y = (kg + 1 <= gi) ? f2bf(v.y) : (unsigned short)0;
            o.z = (kg + 2 <= gi) ? f2bf(v.z) : (unsigned short)0;
            o.w = (kg + 3 <= gi) ? f2bf(v.w) : (unsigned short)0;
            *(ushort4*)&out[swz_byte(row, c4 * 2) >> 1] = o;
        }
    } else {
        // ---- zero C tiles (r0-verified enumeration): 496 strict-upper + 300 lower d>=8 ----
        const int t = b - 4224;
        int bi, bj;
        if (t < 496) {
            int u = t;
            int e = (int)((sqrtf(8.f * (float)u + 1.f) - 1.f) * 0.5f);
            while ((e + 1) * (e + 2) / 2 <= u) ++e;
            while (e * (e + 1) / 2 > u) --e;
            int r = u - e * (e + 1) / 2;
            bi = r; bj = e + 1;
        } else {
            int u = t - 496;
            int d = 8;
            for (; d < 32; ++d) { int cnt = 32 - d; if (u < cnt) break; u -= cnt; }
            bj = u; bi = u + d;
        }
        const float4 z = make_float4(0.f, 0.f, 0.f, 0.f);
        #pragma unroll
        for (int it = 0; it < 16; ++it) {
            int idx = it * 256 + tid;
            int rr  = idx >> 5;
            int c4  = (idx & 31) << 2;
            *(float4*)&C[(size_t)(bi * 128 + rr) * NN + bj * 128 + c4] = z;
        }
    }
}

// ---------------- main GEMM: r0 structure (74us anchor) + packed/swizzled feed ----------------
// 128x128 tile, BK=32, 1000 units: unit -> (d, tile, k-chunk), m = ceil((d+1)/8), <=32 steps.
// 16KB LDS, 256 threads, launch_bounds(256,2): ~4-8 co-resident blocks/CU (the verified feed
// mechanism). Only change vs r0: staging is two contiguous 1KB-burst load_lds16 per matrix
// from the packed layout, and ds_reads use the conflict-free swizzle (r3-verified, 0 conflicts).
__global__ __launch_bounds__(256, 2) void gemm_tril_sk(const unsigned short* __restrict__ A2,
                                                       const unsigned short* __restrict__ B2,
                                                       float* __restrict__ C) {
    const int tid = threadIdx.x;

    // decode unit id -> (bi, bj, chunk c, chunks-per-tile m)  [r0 verbatim]
    int u = blockIdx.x, d, m = 1;
    for (d = 0; d < 32; ++d) {
        m = (d + 8) >> 3;                       // ceil((d+1)/8)
        int cnt = (32 - d) * m;
        if (u < cnt) break;
        u -= cnt;
    }
    const int blk = u / m;
    const int c   = u - blk * m;
    const int bj = blk, bi = blk + d;

    __shared__ __attribute__((aligned(16))) unsigned short As[4096];   // 8KB packed tile
    __shared__ __attribute__((aligned(16))) unsigned short Bs[4096];   // 8KB

    const int lane = tid & 63;
    const int w    = tid >> 6;
    const int wm   = w >> 1, wn = w & 1;
    const int l15  = lane & 15, quad = lane >> 4;

    f32x4 acc[4][4];
    const f32x4 zero4 = {0.f, 0.f, 0.f, 0.f};
    #pragma unroll
    for (int i = 0; i < 4; ++i)
        #pragma unroll
        for (int j = 0; j < 4; ++j) acc[i][j] = zero4;

    const int kbB = (bj << 2) + c * 32;
    const int kbE = min(kbB + 32, (bi << 2) + 4);   // exclusive

    const unsigned short* Abase = A2 + (size_t)bi * 524288 + tid * 8;  // bi*128*4096
    const unsigned short* Bbase = B2 + (size_t)bj * 524288 + tid * 8;

    for (int kb = kbB; kb < kbE; ++kb) {
        const unsigned short* ga = Abase + (size_t)kb * 4096;
        const unsigned short* gb = Bbase + (size_t)kb * 4096;
        load_lds16(ga,        &As[tid * 8]);
        load_lds16(ga + 2048, &As[2048 + tid * 8]);
        load_lds16(gb,        &Bs[tid * 8]);
        load_lds16(gb + 2048, &Bs[2048 + tid * 8]);
        __syncthreads();

        short8 a[4], bfr[4];
        #pragma unroll
        for (int mt = 0; mt < 4; ++mt)
            a[mt] = *(const short8*)&As[swz_byte(wm * 64 + mt * 16 + l15, quad * 16) >> 1];
        #pragma unroll
        for (int nt = 0; nt < 4; ++nt)
            bfr[nt] = *(const short8*)&Bs[swz_byte(wn * 64 + nt * 16 + l15, quad * 16) >> 1];
        #pragma unroll
        for (int mt = 0; mt < 4; ++mt)
            #pragma unroll
            for (int nt = 0; nt < 4; ++nt)
                acc[mt][nt] = __builtin_amdgcn_mfma_f32_16x16x32_bf16(a[mt], bfr[nt], acc[mt][nt], 0, 0, 0);
        __syncthreads();
    }

    // epilogue [r0 verbatim]: C/D layout col=lane&15, row=quad*4+reg (m89-verified)
    if (m == 1) {
        #pragma unroll
        for (int mt = 0; mt < 4; ++mt) {
            #pragma unroll
            for (int nt = 0; nt < 4; ++nt) {
                const int gj  = bj * 128 + wn * 64 + nt * 16 + l15;
                const int gi0 = bi * 128 + wm * 64 + mt * 16 + quad * 4;
                #pragma unroll
                for (int rr = 0; rr < 4; ++rr) {
                    int gi = gi0 + rr;
                    float v = acc[mt][nt][rr];
                    C[(size_t)gi * NN + gj] = (d > 0 || gi >= gj) ? v : 0.f;
                }
            }
        }
    } else {
        // partial contribution: tile pre-zeroed; d>=8 so strictly lower, no mask
        #pragma unroll
        for (int mt = 0; mt < 4; ++mt) {
            #pragma unroll
            for (int nt = 0; nt < 4; ++nt) {
                const int gj  = bj * 128 + wn * 64 + nt * 16 + l15;
                const int gi0 = bi * 128 + wm * 64 + mt * 16 + quad * 4;
                #pragma unroll
                for (int rr = 0; rr < 4; ++rr) {
                    int gi = gi0 + rr;
                    atomicAdd(&C[(size_t)gi * NN + gj], acc[mt][nt][rr]);
                }
            }
        }
    }
}

// ---------------- fallback (ws too small): fp32 LDS-tiled, correct-but-slow ----------------
__global__ void gemm_fallback(const float* __restrict__ A, const float* __restrict__ B,
                              float* __restrict__ C) {
    const int bi = blockIdx.y, bj = blockIdx.x;
    const int ty = threadIdx.y, tx = threadIdx.x;
    const int gi = bi * 32 + ty, gj = bj * 32 + tx;
    if (bi < bj) { C[(size_t)gi * NN + gj] = 0.f; return; }
    __shared__ float As[32][33], Bs[32][33];
    float s = 0.f;
    for (int kt = bj; kt <= bi; ++kt) {
        const int k = kt * 32;
        float av = A[(size_t)gi * NN + k + tx];
        As[ty][tx] = (k + tx <= gi) ? av : 0.f;
        float bv = B[(size_t)(k + ty) * NN + gj];
        Bs[ty][tx] = (k + ty >= gj) ? bv : 0.f;
        __syncthreads();
        #pragma unroll
        for (int kk = 0; kk < 32; ++kk) s += As[ty][kk] * Bs[kk][tx];
        __syncthreads();
    }
    C[(size_t)gi * NN + gj] = (gi >= gj) ? s : 0.f;
}

extern "C" void kernel_launch(void* const* d_in, const int* in_sizes, int n_in,
                              void* d_out, int out_size, void* d_ws, size_t ws_size,
                              hipStream_t stream) {
    const float* A = (const float*)d_in[0];
    const float* B = (const float*)d_in[1];
    float* C = (float*)d_out;

    const size_t need = (size_t)2 * NN * NN * sizeof(unsigned short);  // 64 MB (2 x 32MB packed)
    if (ws_size >= need) {
        unsigned short* A2 = (unsigned short*)d_ws;
        unsigned short* B2 = A2 + (size_t)NN * NN;
        prep_all<<<dim3(5020), dim3(256), 0, stream>>>(A, B, A2, B2, C);
        gemm_tril_sk<<<dim3(1000), dim3(256), 0, stream>>>(A2, B2, C);
    } else {
        gemm_fallback<<<dim3(128, 128), dim3(32, 32), 0, stream>>>(A, B, C);
    }
}